// Round 2
// baseline (291.436 us; speedup 1.0000x reference)
//
#include <hip/hip_runtime.h>
#include <hip/hip_bf16.h>
#include <stdint.h>

typedef __attribute__((ext_vector_type(8))) short bf16x8;
typedef __attribute__((ext_vector_type(4))) float f32x4;

__device__ __forceinline__ unsigned short f2bf(float f) {
  unsigned int u = __float_as_uint(f);
  u = u + 0x7fffu + ((u >> 16) & 1u);   // RNE
  return (unsigned short)(u >> 16);
}

// ---------------- prep kernels ----------------
__global__ void k_style(const float* __restrict__ style, const float* __restrict__ mw,
                        const float* __restrict__ mb, float* __restrict__ s) {
  __shared__ float st[512];
  const int b = blockIdx.x, t = threadIdx.x;
  st[t]       = style[b*512 + t];
  st[t + 256] = style[b*512 + t + 256];
  __syncthreads();
  for (int k = 0; k < 2; ++k) {
    int c = t + k*256;
    const float* row = mw + (size_t)c * 512;
    float acc = 0.f;
    for (int j = 0; j < 512; ++j) acc += st[j] * row[j];
    s[b*512 + c] = acc * 0.04419417382415922f + mb[c];  // 1/sqrt(512)
  }
}

__global__ void k_wsq(const float* __restrict__ w, float* __restrict__ wsq) {
  int g = blockIdx.x * 256 + threadIdx.x;     // o*512+ci
  const float* p = w + (size_t)g * 9;
  float acc = 0.f;
  #pragma unroll
  for (int t = 0; t < 9; ++t) { float v = p[t]; acc += v*v; }
  wsq[g] = acc;
}

__global__ void k_demod(const float* __restrict__ s, const float* __restrict__ wsq,
                        float* __restrict__ dm) {
  __shared__ float s2[512];
  const int g = blockIdx.x * 256 + threadIdx.x;
  const int b = g >> 9, o = g & 511, t = threadIdx.x;
  float v0 = s[b*512 + t], v1 = s[b*512 + t + 256];
  s2[t] = v0*v0; s2[t+256] = v1*v1;
  __syncthreads();
  const float* row = wsq + (size_t)o * 512;
  float acc = 0.f;
  for (int j = 0; j < 512; ++j) acc += s2[j] * row[j];
  dm[g] = rsqrtf(acc * (1.0f/4608.0f) + 1e-8f);
}

// wp[b][kk][cb][o][64ci] bf16, byte-in-row XOR-swizzled with ((o&7)<<4) so that a
// LINEAR global_load_lds of a 128x128B tile yields the swizzled LDS layout.
__global__ void k_wprep(const float* __restrict__ w, const float* __restrict__ s,
                        const float* __restrict__ dm, unsigned short* __restrict__ wp) {
  const int g = blockIdx.x * 256 + threadIdx.x;    // b*512*512 + o*512 + ci
  const int ci = g & 511, o = (g >> 9) & 511, b = g >> 18;
  const float m = 0.014731391274719739f /*1/sqrt(4608)*/ * s[b*512 + ci] * dm[b*512 + o];
  const float* w9 = w + ((size_t)o*512 + ci) * 9;
  const int cb = ci >> 6, cin = ci & 63;
  char* base = (char*)wp;
  const unsigned sw = (unsigned)(cin*2) ^ (unsigned)((o & 7) << 4);
  #pragma unroll
  for (int kk = 0; kk < 9; ++kk) {
    unsigned short h = f2bf(w9[kk] * m);
    size_t off = ((((size_t)b*9 + kk)*8 + cb)*512 + o) * 128 + sw;
    *(unsigned short*)(base + off) = h;
  }
}

// ---------------- conv kernel ----------------
// grid (16 pixel-tiles, 4 o-tiles, 8 batch), block 512 = 8 waves (2m x 4n),
// wave tile 64o x 64px (one output row per wave-col). Block tile 128o x 256px (4 rows).
// LDS A: 2 x [128 o][128B swizzled 64ci]   (double-buffered per (cb,kk))   32 KB
// LDS B: [6 rows][64 x][128B swizzled 64ci] (single-buffered per cb)       48 KB
// Total 80 KB -> 2 blocks/CU -> 16 waves/CU.
__global__ __launch_bounds__(512, 4) void k_conv(const float* __restrict__ in,
                                                 const unsigned short* __restrict__ wp,
                                                 float* __restrict__ out) {
  __shared__ __align__(16) unsigned char ldsA[32768];
  __shared__ __align__(16) unsigned char ldsB[49152];

  const int tid = threadIdx.x;
  const int lan15 = tid & 15;
  const int lgrp = (tid >> 4) & 3;
  const int wid = tid >> 6;
  const int wm = wid >> 2, wn = wid & 3;       // 2 x 4 waves
  const int pt = blockIdx.x, ot = blockIdx.y, b = blockIdx.z;
  const int o0 = ot * 128, y0 = pt * 4;

  const float* inb = in + (size_t)b * 512 * 4096;
  const unsigned short* wpb = wp + (size_t)b * 9 * 8 * 512 * 64;

  auto stageA = [&](int kk, int cb, int par) {
    const char* src = (const char*)(wpb + (((size_t)kk*8 + cb)*512 + (size_t)o0) * 64);
    unsigned char* dst = ldsA + (par << 14);
    #pragma unroll
    for (int r = 0; r < 2; ++r) {
      __builtin_amdgcn_global_load_lds(
        (const __attribute__((address_space(1))) unsigned int*)(src + tid*16 + r*8192),
        (__attribute__((address_space(3))) unsigned int*)(dst + tid*16 + r*8192),
        16, 0, 0);
    }
  };

  // B tile: rows y0-1 .. y0+4 (6), f32->bf16 pack, zero-filled halo rows.
  auto stageB = [&](int cb) {
    #pragma unroll
    for (int j = 0; j < 6; ++j) {
      const int u = tid + j*512;       // 0..3071
      const int cp = u & 31;           // ci-pair (2 planes)
      const int xq = (u >> 5) & 15;    // x quad
      const int r  = u >> 9;           // 0..5
      const int yi = y0 - 1 + r;
      f32x4 v0 = (f32x4){0.f,0.f,0.f,0.f}, v1 = v0;
      if (yi >= 0 && yi < 64) {
        const float* p0 = inb + ((size_t)(cb*64 + cp*2) * 64 + yi) * 64 + xq*4;
        v0 = *(const f32x4*)p0;
        v1 = *(const f32x4*)(p0 + 4096);
      }
      #pragma unroll
      for (int e = 0; e < 4; ++e) {
        const int x = xq*4 + e;
        unsigned int pk = (unsigned)f2bf(v0[e]) | ((unsigned)f2bf(v1[e]) << 16);
        *(unsigned int*)(ldsB + r*8192 + x*128 + ((cp*4) ^ ((x & 7) << 4))) = pk;
      }
    }
  };

  stageB(0);
  stageA(0, 0, 0);

  f32x4 acc[4][4];
  #pragma unroll
  for (int mf = 0; mf < 4; ++mf)
    #pragma unroll
    for (int nf = 0; nf < 4; ++nf)
      acc[mf][nf] = (f32x4){0.f, 0.f, 0.f, 0.f};

  int aOff[4];
  #pragma unroll
  for (int mf = 0; mf < 4; ++mf) {
    int o_rel = wm*64 + mf*16 + lan15;
    aOff[mf] = o_rel*128 + ((lgrp*16) ^ ((o_rel & 7) << 4));
  }
  int cOff[3][4];
  #pragma unroll
  for (int kx = 0; kx < 3; ++kx)
    #pragma unroll
    for (int nf = 0; nf < 4; ++nf) {
      int x = nf*16 + lan15 + kx - 1;
      int ic = x < 0 ? 0 : (x > 63 ? 63 : x);   // clamped; edge lanes zeroed at use
      cOff[kx][nf] = ic*128 + ((lgrp*16) ^ ((ic & 7) << 4));
    }
  const bool zL = (lan15 == 0), zR = (lan15 == 15);

  for (int cb = 0; cb < 8; ++cb) {
    #pragma unroll
    for (int kk = 0; kk < 9; ++kk) {
      const int gg = cb*9 + kk;
      __syncthreads();               // publishes A(gg) [vmcnt drain] and B(cb)
      if (gg < 71) {
        const int nkk = (kk == 8) ? 0 : kk + 1;
        const int ncb = (kk == 8) ? cb + 1 : cb;
        stageA(nkk, ncb, (gg + 1) & 1);
      }
      const int ky = kk / 3, kx = kk % 3;
      const unsigned char* Ab = ldsA + ((gg & 1) << 14);
      const unsigned char* Bb = ldsB + (wn + ky) * 8192;  // input row = wn + ky
      #pragma unroll
      for (int ks = 0; ks < 2; ++ks) {
        bf16x8 af[4], bfr[4];
        #pragma unroll
        for (int mf = 0; mf < 4; ++mf)
          af[mf] = *(const bf16x8*)(Ab + (aOff[mf] ^ (ks << 6)));
        #pragma unroll
        for (int nf = 0; nf < 4; ++nf) {
          bf16x8 v = *(const bf16x8*)(Bb + (cOff[kx][nf] ^ (ks << 6)));
          if (kx == 0 && nf == 0) { if (zL) v = bf16x8{0,0,0,0,0,0,0,0}; }
          if (kx == 2 && nf == 3) { if (zR) v = bf16x8{0,0,0,0,0,0,0,0}; }
          bfr[nf] = v;
        }
        #pragma unroll
        for (int mf = 0; mf < 4; ++mf)
          #pragma unroll
          for (int nf = 0; nf < 4; ++nf)
            acc[mf][nf] = __builtin_amdgcn_mfma_f32_16x16x32_bf16(af[mf], bfr[nf], acc[mf][nf], 0, 0, 0);
      }
      if (kk == 8 && cb < 7) {
        __syncthreads();             // all waves done reading B(cb)
        stageB(cb + 1);
      }
    }
  }

  float* outb = out + (size_t)b * 512 * 4096;
  #pragma unroll
  for (int mf = 0; mf < 4; ++mf) {
    const int o = o0 + wm*64 + mf*16 + lgrp*4;
    #pragma unroll
    for (int nf = 0; nf < 4; ++nf) {
      const int p = pt*256 + wn*64 + nf*16 + lan15;
      #pragma unroll
      for (int r = 0; r < 4; ++r)
        outb[(size_t)(o + r) * 4096 + p] = acc[mf][nf][r];
    }
  }
}

extern "C" void kernel_launch(void* const* d_in, const int* in_sizes, int n_in,
                              void* d_out, int out_size, void* d_ws, size_t ws_size,
                              hipStream_t stream) {
  const float* input  = (const float*)d_in[0];
  const float* style  = (const float*)d_in[1];
  const float* weight = (const float*)d_in[2];
  const float* mw     = (const float*)d_in[3];
  const float* mb     = (const float*)d_in[4];
  float* out = (float*)d_out;
  char* ws = (char*)d_ws;
  float* s     = (float*)ws;                       // 16 KB
  float* demod = (float*)(ws + 16384);             // 16 KB
  float* wsq   = (float*)(ws + 32768);             // 1 MB
  unsigned short* wp = (unsigned short*)(ws + 32768 + 1048576);  // 36 MB

  hipLaunchKernelGGL(k_style, dim3(8),    dim3(256), 0, stream, style, mw, mb, s);
  hipLaunchKernelGGL(k_wsq,   dim3(1024), dim3(256), 0, stream, weight, wsq);
  hipLaunchKernelGGL(k_demod, dim3(16),   dim3(256), 0, stream, s, wsq, demod);
  hipLaunchKernelGGL(k_wprep, dim3(8192), dim3(256), 0, stream, weight, s, demod, wp);
  hipLaunchKernelGGL(k_conv,  dim3(16, 4, 8), dim3(512), 0, stream, input, wp, out);
}

// Round 3
// 245.460 us; speedup vs baseline: 1.1873x; 1.1873x over previous
//
#include <hip/hip_runtime.h>
#include <hip/hip_bf16.h>
#include <stdint.h>

typedef __attribute__((ext_vector_type(8))) short bf16x8;
typedef __attribute__((ext_vector_type(4))) float f32x4;
typedef __attribute__((ext_vector_type(8))) unsigned short u16x8;

__device__ __forceinline__ unsigned short f2bf(float f) {
  unsigned int u = __float_as_uint(f);
  u = u + 0x7fffu + ((u >> 16) & 1u);   // RNE
  return (unsigned short)(u >> 16);
}

// ---------------- prep kernels ----------------
__global__ void k_style(const float* __restrict__ style, const float* __restrict__ mw,
                        const float* __restrict__ mb, float* __restrict__ s) {
  __shared__ float st[512];
  const int b = blockIdx.x, t = threadIdx.x;
  st[t]       = style[b*512 + t];
  st[t + 256] = style[b*512 + t + 256];
  __syncthreads();
  for (int k = 0; k < 2; ++k) {
    int c = t + k*256;
    const float* row = mw + (size_t)c * 512;
    float acc = 0.f;
    for (int j = 0; j < 512; ++j) acc += st[j] * row[j];
    s[b*512 + c] = acc * 0.04419417382415922f + mb[c];  // 1/sqrt(512)
  }
}

__global__ void k_wsq(const float* __restrict__ w, float* __restrict__ wsq) {
  int g = blockIdx.x * 256 + threadIdx.x;     // o*512+ci
  const float* p = w + (size_t)g * 9;
  float acc = 0.f;
  #pragma unroll
  for (int t = 0; t < 9; ++t) { float v = p[t]; acc += v*v; }
  wsq[g] = acc;
}

__global__ void k_demod(const float* __restrict__ s, const float* __restrict__ wsq,
                        float* __restrict__ dm) {
  __shared__ float s2[512];
  const int g = blockIdx.x * 256 + threadIdx.x;
  const int b = g >> 9, o = g & 511, t = threadIdx.x;
  float v0 = s[b*512 + t], v1 = s[b*512 + t + 256];
  s2[t] = v0*v0; s2[t+256] = v1*v1;
  __syncthreads();
  const float* row = wsq + (size_t)o * 512;
  float acc = 0.f;
  for (int j = 0; j < 512; ++j) acc += s2[j] * row[j];
  dm[g] = rsqrtf(acc * (1.0f/4608.0f) + 1e-8f);
}

// transpose w[o][ci][kk] -> wt[kk][cb][o][64ci] (f32), coalesced 32B writes
__global__ void k_wt(const float* __restrict__ w, float* __restrict__ wt) {
  const int id = blockIdx.x * 256 + threadIdx.x;   // < 294912
  const int c8 = id & 7, o = (id >> 3) & 511, cb = (id >> 12) & 7, kk = id >> 15;
  const int ci0 = cb*64 + c8*8;
  float v[8];
  #pragma unroll
  for (int e = 0; e < 8; ++e) v[e] = w[((size_t)(o*512 + ci0 + e))*9 + kk];
  float* dst = wt + (((size_t)(kk*8 + cb)*512 + o)*64 + c8*8);
  *(f32x4*)dst       = (f32x4){v[0],v[1],v[2],v[3]};
  *(f32x4*)(dst + 4) = (f32x4){v[4],v[5],v[6],v[7]};
}

// wp[b][kk][cb][o][64ci] bf16, byte-in-row XOR-swizzled with ((o&7)<<4);
// fully coalesced 16B stores.
__global__ void k_wprep2(const float* __restrict__ wt, const float* __restrict__ s,
                         const float* __restrict__ dm, unsigned short* __restrict__ wp) {
  const int id = blockIdx.x * 256 + threadIdx.x;   // < 294912
  const int b = blockIdx.y;
  const int c8 = id & 7, o = (id >> 3) & 511, cb = (id >> 12) & 7, kk = id >> 15;
  const int ci0 = cb*64 + c8*8;
  const float dmo = 0.014731391274719739f /*1/sqrt(4608)*/ * dm[b*512 + o];
  f32x4 s0 = *(const f32x4*)(s + b*512 + ci0);
  f32x4 s1 = *(const f32x4*)(s + b*512 + ci0 + 4);
  const float* src = wt + (((size_t)(kk*8 + cb)*512 + o)*64 + c8*8);
  f32x4 w0 = *(const f32x4*)src, w1 = *(const f32x4*)(src + 4);
  u16x8 h;
  #pragma unroll
  for (int e = 0; e < 4; ++e) h[e]     = f2bf(w0[e] * s0[e] * dmo);
  #pragma unroll
  for (int e = 0; e < 4; ++e) h[e + 4] = f2bf(w1[e] * s1[e] * dmo);
  char* base = (char*)wp + ((((size_t)b*9 + kk)*8 + cb)*512 + o)*128
             + ((unsigned)(c8*16) ^ (unsigned)((o & 7) << 4));
  *(u16x8*)base = h;
}

// ---------------- conv kernel ----------------
// 512 blocks (XCD-swizzled), 512 threads = 8 waves (2m x 4n), wave 64o x 64px.
// Block tile 128o x 256px (4 rows). Counted-vmcnt pipeline:
//   LDS A: 3 x 16 KB (prefetch distance 2 via global_load_lds)
//   LDS B: 2 x 48 KB (double-buffered; loads at kk==0, ds_write at kk==4)
// 144 KB LDS -> 1 block/CU, raw s_barrier + counted vmcnt (never 0 mid-loop).
__global__ __launch_bounds__(512, 2) void k_conv(const float* __restrict__ in,
                                                 const unsigned short* __restrict__ wp,
                                                 float* __restrict__ out) {
  __shared__ __align__(16) unsigned char ldsA[3*16384];
  __shared__ __align__(16) unsigned char ldsB[2*49152];

  const int tid = threadIdx.x;
  const int lan15 = tid & 15;
  const int lgrp = (tid >> 4) & 3;
  const int wid = tid >> 6;
  const int wm = wid >> 2, wn = wid & 3;
  // XCD swizzle: all 16 pt-blocks of one (b,ot) group land on one XCD.
  const unsigned wg = blockIdx.x;
  const int g8 = wg & 7, pt = (wg >> 3) & 15, ghi = wg >> 7;
  const int g = ghi*8 + g8;            // 0..31
  const int ot = g & 3, b = g >> 2;
  const int o0 = ot * 128, y0 = pt * 4;

  const float* inb = in + (size_t)b * 512 * 4096;
  const unsigned short* wpb = wp + (size_t)b * 9 * 8 * 512 * 64;

  auto stageA = [&](int tap, int cbb, int buf) {
    const char* src = (const char*)(wpb + (((size_t)tap*8 + cbb)*512 + (size_t)o0) * 64);
    unsigned char* dst = ldsA + buf*16384;
    #pragma unroll
    for (int r = 0; r < 2; ++r) {
      __builtin_amdgcn_global_load_lds(
        (const __attribute__((address_space(1))) unsigned int*)(src + tid*16 + r*8192),
        (__attribute__((address_space(3))) unsigned int*)(dst + tid*16 + r*8192),
        16, 0, 0);
    }
  };

  f32x4 bv0[6], bv1[6];
  auto loadB = [&](int cbb) {           // uniform 12 loads/thread (rows clamped)
    const int cp = tid & 31, xq = (tid >> 5) & 15;
    #pragma unroll
    for (int j = 0; j < 6; ++j) {
      const int yi = y0 - 1 + j;
      const int yc = yi < 0 ? 0 : (yi > 63 ? 63 : yi);
      const float* p0 = inb + ((size_t)(cbb*64 + cp*2) * 64 + yc) * 64 + xq*4;
      bv0[j] = *(const f32x4*)p0;
      bv1[j] = *(const f32x4*)(p0 + 4096);
    }
  };
  auto writeB = [&](int dstbuf) {
    unsigned char* base = ldsB + dstbuf*49152;
    const int cp = tid & 31, xq = (tid >> 5) & 15;
    #pragma unroll
    for (int j = 0; j < 6; ++j) {
      const int yi = y0 - 1 + j;
      const bool valid = (yi >= 0) & (yi < 64);
      #pragma unroll
      for (int e = 0; e < 4; ++e) {
        const int x = xq*4 + e;
        unsigned pk = valid ? ((unsigned)f2bf(bv0[j][e]) | ((unsigned)f2bf(bv1[j][e]) << 16)) : 0u;
        *(unsigned*)(base + j*8192 + x*128 + ((cp*4) ^ ((x & 7) << 4))) = pk;
      }
    }
  };

  f32x4 acc[4][4];
  #pragma unroll
  for (int mf = 0; mf < 4; ++mf)
    #pragma unroll
    for (int nf = 0; nf < 4; ++nf)
      acc[mf][nf] = (f32x4){0.f, 0.f, 0.f, 0.f};

  int aOff[4];
  #pragma unroll
  for (int mf = 0; mf < 4; ++mf) {
    int o_rel = wm*64 + mf*16 + lan15;
    aOff[mf] = o_rel*128 + ((lgrp*16) ^ ((o_rel & 7) << 4));
  }
  int cOff[3][4];
  #pragma unroll
  for (int kx = 0; kx < 3; ++kx)
    #pragma unroll
    for (int nf = 0; nf < 4; ++nf) {
      int x = nf*16 + lan15 + kx - 1;
      int ic = x < 0 ? 0 : (x > 63 ? 63 : x);
      cOff[kx][nf] = ic*128 + ((lgrp*16) ^ ((ic & 7) << 4));
    }
  const bool zL = (lan15 == 0), zR = (lan15 == 15);

#define ENDB(N) asm volatile("s_waitcnt vmcnt(" #N ")\n\ts_barrier" ::: "memory")

#define COMPUTE(KK, BRB) { \
    constexpr int ky_ = (KK)/3, kx_ = (KK)%3; \
    const unsigned char* Ab = ldsA + ((KK)%3)*16384; \
    const unsigned char* Bb = (BRB) + (wn + ky_)*8192; \
    __builtin_amdgcn_s_setprio(1); \
    _Pragma("unroll") \
    for (int ks = 0; ks < 2; ++ks) { \
      bf16x8 af[4], bfr[4]; \
      _Pragma("unroll") \
      for (int mf = 0; mf < 4; ++mf) \
        af[mf] = *(const bf16x8*)(Ab + (aOff[mf] ^ (ks << 6))); \
      _Pragma("unroll") \
      for (int nf = 0; nf < 4; ++nf) { \
        bf16x8 v = *(const bf16x8*)(Bb + (cOff[kx_][nf] ^ (ks << 6))); \
        if (kx_ == 0 && nf == 0) { if (zL) v = (bf16x8){0,0,0,0,0,0,0,0}; } \
        if (kx_ == 2 && nf == 3) { if (zR) v = (bf16x8){0,0,0,0,0,0,0,0}; } \
        bfr[nf] = v; \
      } \
      _Pragma("unroll") \
      for (int mf = 0; mf < 4; ++mf) \
        _Pragma("unroll") \
        for (int nf = 0; nf < 4; ++nf) \
          acc[mf][nf] = __builtin_amdgcn_mfma_f32_16x16x32_bf16(af[mf], bfr[nf], acc[mf][nf], 0, 0, 0); \
    } \
    __builtin_amdgcn_s_setprio(0); }

  // prologue: B0 regs, A0+A1 in flight, write B0, full drain once.
  loadB(0);
  stageA(0, 0, 0);
  stageA(1, 0, 1);
  writeB(0);
  __syncthreads();

  for (int cb = 0; cb < 7; ++cb) {
    const unsigned char* Br = ldsB + (cb & 1)*49152;
    const int wb = (cb & 1) ^ 1;
#define IT(KK, NW) { \
      stageA(((KK)+2)%9, cb + ((KK)+2)/9, ((KK)+2)%3); \
      if ((KK) == 0) loadB(cb + 1); \
      if ((KK) == 4) { writeB(wb); asm volatile("s_waitcnt lgkmcnt(0)" ::: "memory"); } \
      COMPUTE(KK, Br); \
      ENDB(NW); }
    IT(0,14) IT(1,14) IT(2,2) IT(3,2) IT(4,2) IT(5,2) IT(6,2) IT(7,2) IT(8,2)
#undef IT
  }
  { // cb == 7 tail (no B staging; exact vmcnt drains)
    const unsigned char* Br = ldsB + 49152;
    stageA(2,7,2); COMPUTE(0, Br); ENDB(2);
    stageA(3,7,0); COMPUTE(1, Br); ENDB(2);
    stageA(4,7,1); COMPUTE(2, Br); ENDB(2);
    stageA(5,7,2); COMPUTE(3, Br); ENDB(2);
    stageA(6,7,0); COMPUTE(4, Br); ENDB(2);
    stageA(7,7,1); COMPUTE(5, Br); ENDB(2);
    stageA(8,7,2); COMPUTE(6, Br); ENDB(2);
    COMPUTE(7, Br); ENDB(0);
    COMPUTE(8, Br);
  }

  float* outb = out + (size_t)b * 512 * 4096;
  #pragma unroll
  for (int mf = 0; mf < 4; ++mf) {
    const int o = o0 + wm*64 + mf*16 + lgrp*4;
    #pragma unroll
    for (int nf = 0; nf < 4; ++nf) {
      const int p = pt*256 + wn*64 + nf*16 + lan15;
      #pragma unroll
      for (int r = 0; r < 4; ++r)
        outb[(size_t)(o + r) * 4096 + p] = acc[mf][nf][r];
    }
  }
#undef COMPUTE
#undef ENDB
}

extern "C" void kernel_launch(void* const* d_in, const int* in_sizes, int n_in,
                              void* d_out, int out_size, void* d_ws, size_t ws_size,
                              hipStream_t stream) {
  const float* input  = (const float*)d_in[0];
  const float* style  = (const float*)d_in[1];
  const float* weight = (const float*)d_in[2];
  const float* mw     = (const float*)d_in[3];
  const float* mb     = (const float*)d_in[4];
  float* out = (float*)d_out;
  char* ws = (char*)d_ws;
  float* s     = (float*)ws;                         // 16 KB
  float* demod = (float*)(ws + 16384);               // 16 KB
  float* wsq   = (float*)(ws + 32768);               // 1 MB
  float* wt    = (float*)(ws + 1081344);             // 9.4 MB
  unsigned short* wp = (unsigned short*)(ws + 10518528);  // 36 MB

  hipLaunchKernelGGL(k_style,  dim3(8),        dim3(256), 0, stream, style, mw, mb, s);
  hipLaunchKernelGGL(k_wsq,    dim3(1024),     dim3(256), 0, stream, weight, wsq);
  hipLaunchKernelGGL(k_wt,     dim3(1152),     dim3(256), 0, stream, weight, wt);
  hipLaunchKernelGGL(k_demod,  dim3(16),       dim3(256), 0, stream, s, wsq, demod);
  hipLaunchKernelGGL(k_wprep2, dim3(1152, 8),  dim3(256), 0, stream, wt, s, demod, wp);
  hipLaunchKernelGGL(k_conv,   dim3(512),      dim3(512), 0, stream, input, wp, out);
}

// Round 4
// 214.246 us; speedup vs baseline: 1.3603x; 1.1457x over previous
//
#include <hip/hip_runtime.h>
#include <hip/hip_bf16.h>
#include <stdint.h>

typedef __attribute__((ext_vector_type(8))) short bf16x8;
typedef __attribute__((ext_vector_type(4))) float f32x4;
typedef __attribute__((ext_vector_type(8))) unsigned short u16x8;

__device__ __forceinline__ unsigned short f2bf(float f) {
  unsigned int u = __float_as_uint(f);
  u = u + 0x7fffu + ((u >> 16) & 1u);   // RNE
  return (unsigned short)(u >> 16);
}

// ---------------- prep kernels ----------------
// blocks 0-7: style modulation s[b][c]; blocks 8..1031: wsq[o][ci]
__global__ void k_sw(const float* __restrict__ style, const float* __restrict__ mw,
                     const float* __restrict__ mb, const float* __restrict__ w,
                     float* __restrict__ s, float* __restrict__ wsq) {
  if (blockIdx.x < 8) {
    __shared__ float st[512];
    const int b = blockIdx.x, t = threadIdx.x;
    st[t]       = style[b*512 + t];
    st[t + 256] = style[b*512 + t + 256];
    __syncthreads();
    for (int k = 0; k < 2; ++k) {
      int c = t + k*256;
      const float* row = mw + (size_t)c * 512;
      float acc = 0.f;
      for (int j = 0; j < 512; ++j) acc += st[j] * row[j];
      s[b*512 + c] = acc * 0.04419417382415922f + mb[c];  // 1/sqrt(512)
    }
  } else {
    int g = (blockIdx.x - 8) * 256 + threadIdx.x;     // o*512+ci
    const float* p = w + (size_t)g * 9;
    float acc = 0.f;
    #pragma unroll
    for (int t = 0; t < 9; ++t) { float v = p[t]; acc += v*v; }
    wsq[g] = acc;
  }
}

__global__ void k_demod(const float* __restrict__ s, const float* __restrict__ wsq,
                        float* __restrict__ dm) {
  __shared__ float s2[512];
  const int g = blockIdx.x * 256 + threadIdx.x;
  const int b = g >> 9, o = g & 511, t = threadIdx.x;
  float v0 = s[b*512 + t], v1 = s[b*512 + t + 256];
  s2[t] = v0*v0; s2[t+256] = v1*v1;
  __syncthreads();
  const float* row = wsq + (size_t)o * 512;
  float acc = 0.f;
  for (int j = 0; j < 512; ++j) acc += s2[j] * row[j];
  dm[g] = rsqrtf(acc * (1.0f/4608.0f) + 1e-8f);
}

// transpose w[o][ci][kk] -> wt[kk][cb][o][64ci] (f32), coalesced 32B writes
__global__ void k_wt(const float* __restrict__ w, float* __restrict__ wt) {
  const int id = blockIdx.x * 256 + threadIdx.x;   // < 294912
  const int c8 = id & 7, o = (id >> 3) & 511, cb = (id >> 12) & 7, kk = id >> 15;
  const int ci0 = cb*64 + c8*8;
  float v[8];
  #pragma unroll
  for (int e = 0; e < 8; ++e) v[e] = w[((size_t)(o*512 + ci0 + e))*9 + kk];
  float* dst = wt + (((size_t)(kk*8 + cb)*512 + o)*64 + c8*8);
  *(f32x4*)dst       = (f32x4){v[0],v[1],v[2],v[3]};
  *(f32x4*)(dst + 4) = (f32x4){v[4],v[5],v[6],v[7]};
}

// wp[b][kk][cb][o][64ci] bf16, byte-in-row XOR-swizzled with ((o&7)<<4);
// fully coalesced 16B stores.
__global__ void k_wprep2(const float* __restrict__ wt, const float* __restrict__ s,
                         const float* __restrict__ dm, unsigned short* __restrict__ wp) {
  const int id = blockIdx.x * 256 + threadIdx.x;   // < 294912
  const int b = blockIdx.y;
  const int c8 = id & 7, o = (id >> 3) & 511, cb = (id >> 12) & 7, kk = id >> 15;
  const int ci0 = cb*64 + c8*8;
  const float dmo = 0.014731391274719739f /*1/sqrt(4608)*/ * dm[b*512 + o];
  f32x4 s0 = *(const f32x4*)(s + b*512 + ci0);
  f32x4 s1 = *(const f32x4*)(s + b*512 + ci0 + 4);
  const float* src = wt + (((size_t)(kk*8 + cb)*512 + o)*64 + c8*8);
  f32x4 w0 = *(const f32x4*)src, w1 = *(const f32x4*)(src + 4);
  u16x8 h;
  #pragma unroll
  for (int e = 0; e < 4; ++e) h[e]     = f2bf(w0[e] * s0[e] * dmo);
  #pragma unroll
  for (int e = 0; e < 4; ++e) h[e + 4] = f2bf(w1[e] * s1[e] * dmo);
  char* base = (char*)wp + ((((size_t)b*9 + kk)*8 + cb)*512 + o)*128
             + ((unsigned)(c8*16) ^ (unsigned)((o & 7) << 4));
  *(u16x8*)base = h;
}

// ---------------- conv kernel ----------------
// 256 blocks (1/CU), 512 threads = 8 waves (2m x 4n), wave tile 128o x 64px.
// Block tile 256o x 256px (4 rows).
//   LDS A: 3 x 32 KB (prefetch distance 2; tap t -> buf t%3)
//   LDS B: 1 x 48 KB (rows y0-1..y0+4; rewritten at cb boundaries)
// Counted vmcnt: ENDB(4) kk=0..6, ENDB(16) kk=7, drain+convert at kk=8.
__global__ __launch_bounds__(512, 2) void k_conv(const float* __restrict__ in,
                                                 const unsigned short* __restrict__ wp,
                                                 float* __restrict__ out) {
  __shared__ __align__(16) unsigned char ldsA[3*32768];
  __shared__ __align__(16) unsigned char ldsB[49152];

  const int tid = threadIdx.x;
  const int lan15 = tid & 15;
  const int lgrp = (tid >> 4) & 3;
  const int wid = tid >> 6;
  const int wm = wid >> 2, wn = wid & 3;
  const unsigned wg = blockIdx.x;
  const int b = wg & 7, pt = (wg >> 3) & 15, ot = (wg >> 7) & 1;   // XCD: all of batch b on one die
  const int o0 = ot * 256, y0 = pt * 4;

  const float* inb = in + (size_t)b * 512 * 4096;
  const unsigned short* wpb = wp + (size_t)b * 9 * 8 * 512 * 64;

  auto stageA = [&](int tap, int cbb, int buf) {
    const char* src = (const char*)(wpb + (((size_t)tap*8 + cbb)*512 + (size_t)o0) * 64);
    unsigned char* dst = ldsA + buf*32768;
    #pragma unroll
    for (int r = 0; r < 4; ++r) {
      __builtin_amdgcn_global_load_lds(
        (const __attribute__((address_space(1))) unsigned int*)(src + tid*16 + r*8192),
        (__attribute__((address_space(3))) unsigned int*)(dst + tid*16 + r*8192),
        16, 0, 0);
    }
  };

  f32x4 bv0[6], bv1[6];
  unsigned bp[6][4];
  auto loadB = [&](int cbb) {           // uniform 12 loads/thread (rows clamped)
    const int cp = tid & 31, xq = (tid >> 5) & 15;
    #pragma unroll
    for (int j = 0; j < 6; ++j) {
      const int yi = y0 - 1 + j;
      const int yc = yi < 0 ? 0 : (yi > 63 ? 63 : yi);
      const float* p0 = inb + ((size_t)(cbb*64 + cp*2) * 64 + yc) * 64 + xq*4;
      bv0[j] = *(const f32x4*)p0;
      bv1[j] = *(const f32x4*)(p0 + 4096);
    }
  };
  auto convB = [&]() {
    #pragma unroll
    for (int j = 0; j < 6; ++j)
      #pragma unroll
      for (int e = 0; e < 4; ++e)
        bp[j][e] = (unsigned)f2bf(bv0[j][e]) | ((unsigned)f2bf(bv1[j][e]) << 16);
  };
  auto writeB = [&]() {
    const int cp = tid & 31, xq = (tid >> 5) & 15;
    #pragma unroll
    for (int j = 0; j < 6; ++j) {
      const int yi = y0 - 1 + j;
      const bool valid = (yi >= 0) & (yi < 64);
      #pragma unroll
      for (int e = 0; e < 4; ++e) {
        const int x = xq*4 + e;
        *(unsigned*)(ldsB + j*8192 + x*128 + ((cp*4) ^ ((x & 7) << 4))) = valid ? bp[j][e] : 0u;
      }
    }
  };

  f32x4 acc[8][4];
  #pragma unroll
  for (int mf = 0; mf < 8; ++mf)
    #pragma unroll
    for (int nf = 0; nf < 4; ++nf)
      acc[mf][nf] = (f32x4){0.f, 0.f, 0.f, 0.f};

  // A fragment base (mf folds into ds-offset imm: +mf*2048; swizzle invariant mod 8)
  const int aB0 = (wm*128 + lan15)*128 + ((lgrp*16) ^ ((lan15 & 7) << 4));
  const int aB1 = aB0 ^ 64;
  // B fragment bases per kx (nf folds: +nf*2048; ky folds: +ky*8192).
  // Edge lanes intentionally unclamped (reads garbage, zeroed below).
  int cB0[3], cB1[3];
  #pragma unroll
  for (int kx = 0; kx < 3; ++kx) {
    const int x0 = lan15 + kx - 1;
    cB0[kx] = wn*8192 + x0*128 + ((lgrp*16) ^ ((x0 & 7) << 4));
    cB1[kx] = cB0[kx] ^ 64;
  }
  const bool zL = (lan15 == 0), zR = (lan15 == 15);

#define ENDB(N) asm volatile("s_waitcnt vmcnt(" #N ")\n\ts_barrier" ::: "memory")

#define COMPUTE(KK) { \
    constexpr int ky_ = (KK)/3, kx_ = (KK)%3; \
    const unsigned char* Ab = ldsA + ((KK)%3)*32768; \
    __builtin_amdgcn_s_setprio(1); \
    _Pragma("unroll") \
    for (int ks = 0; ks < 2; ++ks) { \
      const int aB = ks ? aB1 : aB0; \
      const int cBk = ks ? cB1[kx_] : cB0[kx_]; \
      bf16x8 af[8], bfr[4]; \
      _Pragma("unroll") \
      for (int mf = 0; mf < 8; ++mf) \
        af[mf] = *(const bf16x8*)(Ab + aB + mf*2048); \
      _Pragma("unroll") \
      for (int nf = 0; nf < 4; ++nf) { \
        bf16x8 v = *(const bf16x8*)(ldsB + ky_*8192 + cBk + nf*2048); \
        if (kx_ == 0 && nf == 0) { if (zL) v = (bf16x8){0,0,0,0,0,0,0,0}; } \
        if (kx_ == 2 && nf == 3) { if (zR) v = (bf16x8){0,0,0,0,0,0,0,0}; } \
        bfr[nf] = v; \
      } \
      _Pragma("unroll") \
      for (int mf = 0; mf < 8; ++mf) \
        _Pragma("unroll") \
        for (int nf = 0; nf < 4; ++nf) \
          acc[mf][nf] = __builtin_amdgcn_mfma_f32_16x16x32_bf16(af[mf], bfr[nf], acc[mf][nf], 0, 0, 0); \
    } \
    __builtin_amdgcn_s_setprio(0); }

#define IT6(KK) { stageA((KK)+2, cb, ((KK)+2)%3); COMPUTE(KK); ENDB(4); }

  // prologue: B0 loads, A0+A1 in flight, convert+write B0, single gated barrier.
  loadB(0);
  asm volatile("" ::: "memory");
  stageA(0, 0, 0);
  stageA(1, 0, 1);
  asm volatile("s_waitcnt vmcnt(8)" ::: "memory");   // B done; A0/A1 in flight
  convB();
  writeB();
  asm volatile("s_waitcnt vmcnt(4) lgkmcnt(0)\n\ts_barrier" ::: "memory");  // A0 done

  for (int cb = 0; cb < 7; ++cb) {
    IT6(0) IT6(1) IT6(2) IT6(3) IT6(4) IT6(5) IT6(6)
    // kk == 7: prefetch A(next-cb,0) then B-loads (order pinned for the ledger)
    stageA(0, cb + 1, 0);
    asm volatile("" ::: "memory");
    COMPUTE(7);
    loadB(cb + 1);
    ENDB(16);
    // kk == 8: drain, convert, stage A(next,1), compute, boundary write of B
    asm volatile("s_waitcnt vmcnt(0)" ::: "memory");
    convB();
    stageA(1, cb + 1, 1);
    COMPUTE(8);
    asm volatile("s_barrier" ::: "memory");          // all waves done reading B(cb)
    writeB();
    asm volatile("s_waitcnt lgkmcnt(0)\n\ts_barrier" ::: "memory");
  }
  { // cb == 7 tail
    const int cb = 7;
    IT6(0) IT6(1) IT6(2) IT6(3) IT6(4) IT6(5) IT6(6)
    COMPUTE(7); ENDB(0);
    COMPUTE(8);
  }

  float* outb = out + (size_t)b * 512 * 4096;
  #pragma unroll
  for (int mf = 0; mf < 8; ++mf) {
    const int o = o0 + wm*128 + mf*16 + lgrp*4;
    #pragma unroll
    for (int nf = 0; nf < 4; ++nf) {
      const int p = pt*256 + wn*64 + nf*16 + lan15;
      #pragma unroll
      for (int r = 0; r < 4; ++r)
        outb[(size_t)(o + r) * 4096 + p] = acc[mf][nf][r];
    }
  }
#undef IT6
#undef COMPUTE
#undef ENDB
}

extern "C" void kernel_launch(void* const* d_in, const int* in_sizes, int n_in,
                              void* d_out, int out_size, void* d_ws, size_t ws_size,
                              hipStream_t stream) {
  const float* input  = (const float*)d_in[0];
  const float* style  = (const float*)d_in[1];
  const float* weight = (const float*)d_in[2];
  const float* mw     = (const float*)d_in[3];
  const float* mb     = (const float*)d_in[4];
  float* out = (float*)d_out;
  char* ws = (char*)d_ws;
  float* s     = (float*)ws;                         // 16 KB
  float* demod = (float*)(ws + 16384);               // 16 KB
  float* wsq   = (float*)(ws + 32768);               // 1 MB
  float* wt    = (float*)(ws + 1081344);             // 9.4 MB
  unsigned short* wp = (unsigned short*)(ws + 10518528);  // 36 MB

  hipLaunchKernelGGL(k_wt,     dim3(1152),     dim3(256), 0, stream, weight, wt);
  hipLaunchKernelGGL(k_sw,     dim3(1032),     dim3(256), 0, stream, style, mw, mb, weight, s, wsq);
  hipLaunchKernelGGL(k_demod,  dim3(16),       dim3(256), 0, stream, s, wsq, demod);
  hipLaunchKernelGGL(k_wprep2, dim3(1152, 8),  dim3(256), 0, stream, wt, s, demod, wp);
  hipLaunchKernelGGL(k_conv,   dim3(256),      dim3(512), 0, stream, input, wp, out);
}